// Round 1
// baseline (322.641 us; speedup 1.0000x reference)
//
#include <hip/hip_runtime.h>
#include <math.h>

static constexpr int N_NODES = 50000;
static constexpr int N_EDGES = 800000;
static constexpr int NFEAT = 512;
static constexpr int NHID = 96;
static constexpr int NCLASS = 40;

// ---------------------------------------------------------------------------
// GEMM1: support[M,96] = x[M,512] @ W1[512,96] + b1
// 64-row x 96-col tile per block, K-tiles of 64 staged in LDS.
// 256 threads: tx (0..15) -> 6 cols each, ty (0..15) -> 4 rows each.
// ---------------------------------------------------------------------------
__global__ __launch_bounds__(256) void k_gemm1(const float* __restrict__ x,
                                               const float* __restrict__ W1,
                                               const float* __restrict__ b1,
                                               float* __restrict__ support) {
    __shared__ float xs[64][68];   // [k][row] transposed; stride 68 floats = 272B (16B-aligned, bank-clean)
    __shared__ float wsh[64][96];  // [k][col]
    const int tid = threadIdx.x;
    const int tx = tid & 15;
    const int ty = tid >> 4;
    const int row0 = blockIdx.x * 64;

    float acc[4][6];
#pragma unroll
    for (int i = 0; i < 4; ++i)
#pragma unroll
        for (int j = 0; j < 6; ++j) acc[i][j] = 0.f;

    for (int k0 = 0; k0 < NFEAT; k0 += 64) {
        // stage x tile (transposed into [k][row]) — float4 global loads, coalesced
#pragma unroll
        for (int i = 0; i < 4; ++i) {
            int lid = tid + i * 256;      // float4 id, 1024 total
            int r = lid >> 4;             // 64 rows
            int c4 = (lid & 15) << 2;     // 16 float4 per row
            float4 v = make_float4(0.f, 0.f, 0.f, 0.f);
            int row = row0 + r;
            if (row < N_NODES)
                v = *reinterpret_cast<const float4*>(x + (size_t)row * NFEAT + k0 + c4);
            xs[c4 + 0][r] = v.x;
            xs[c4 + 1][r] = v.y;
            xs[c4 + 2][r] = v.z;
            xs[c4 + 3][r] = v.w;
        }
        // stage W1 tile — tile is contiguous in global, perfectly coalesced float4
#pragma unroll
        for (int i = 0; i < 6; ++i) {
            int lid = tid + i * 256;      // float4 id, 1536 total
            float4 v = *reinterpret_cast<const float4*>(W1 + (size_t)k0 * NHID + lid * 4);
            *reinterpret_cast<float4*>(&wsh[0][0] + lid * 4) = v;
        }
        __syncthreads();
#pragma unroll 8
        for (int kk = 0; kk < 64; ++kk) {
            float4 a4 = *reinterpret_cast<const float4*>(&xs[kk][ty << 2]);
            float2 bb0 = *reinterpret_cast<const float2*>(&wsh[kk][tx * 6]);
            float2 bb1 = *reinterpret_cast<const float2*>(&wsh[kk][tx * 6 + 2]);
            float2 bb2 = *reinterpret_cast<const float2*>(&wsh[kk][tx * 6 + 4]);
            float a[4] = {a4.x, a4.y, a4.z, a4.w};
            float b[6] = {bb0.x, bb0.y, bb1.x, bb1.y, bb2.x, bb2.y};
#pragma unroll
            for (int i = 0; i < 4; ++i)
#pragma unroll
                for (int j = 0; j < 6; ++j) acc[i][j] = fmaf(a[i], b[j], acc[i][j]);
        }
        __syncthreads();
    }
#pragma unroll
    for (int i = 0; i < 4; ++i) {
        int row = row0 + (ty << 2) + i;
        if (row >= N_NODES) continue;
        float* dp = support + (size_t)row * NHID + tx * 6;
#pragma unroll
        for (int j = 0; j < 6; ++j) dp[j] = acc[i][j] + b1[tx * 6 + j];
    }
}

// ---------------------------------------------------------------------------
// CSR build: histogram -> single-block scan -> counting-sort scatter
// ---------------------------------------------------------------------------
__global__ __launch_bounds__(256) void k_hist(const int* __restrict__ dst,
                                              int* __restrict__ deg) {
    int i = blockIdx.x * 256 + threadIdx.x;
    if (i < N_EDGES) atomicAdd(&deg[dst[i]], 1);
}

__global__ __launch_bounds__(1024) void k_scan(const int* __restrict__ deg,
                                               int* __restrict__ row_ptr,
                                               int* __restrict__ cursor) {
    __shared__ int wsum[16];
    __shared__ int s_run;
    const int tid = threadIdx.x;
    const int lane = tid & 63;
    const int wid = tid >> 6;
    if (tid == 0) s_run = 0;
    __syncthreads();
    for (int base = 0; base < N_NODES; base += 1024) {
        int i = base + tid;
        int v = (i < N_NODES) ? deg[i] : 0;
        int xv = v;
#pragma unroll
        for (int off = 1; off < 64; off <<= 1) {
            int y = __shfl_up(xv, off);
            if (lane >= off) xv += y;
        }
        if (lane == 63) wsum[wid] = xv;
        __syncthreads();
        if (wid == 0) {
            int s = (lane < 16) ? wsum[lane] : 0;
#pragma unroll
            for (int off = 1; off < 16; off <<= 1) {
                int y = __shfl_up(s, off);
                if (lane >= off) s += y;
            }
            if (lane < 16) wsum[lane] = s;
        }
        __syncthreads();
        int woff = (wid == 0) ? 0 : wsum[wid - 1];
        int excl = s_run + woff + (xv - v);
        if (i < N_NODES) {
            row_ptr[i] = excl;
            cursor[i] = excl;
        }
        int ctot = wsum[15];
        __syncthreads();
        if (tid == 0) s_run += ctot;
        __syncthreads();
    }
    if (tid == 0) row_ptr[N_NODES] = s_run;
}

__global__ __launch_bounds__(256) void k_scatter(const int* __restrict__ src,
                                                 const int* __restrict__ dst,
                                                 const float* __restrict__ ew,
                                                 int* __restrict__ cursor,
                                                 int2* __restrict__ sorted) {
    int i = blockIdx.x * 256 + threadIdx.x;
    if (i < N_EDGES) {
        int d = dst[i];
        int pos = atomicAdd(&cursor[d], 1);
        sorted[pos] = make_int2(src[i], __float_as_int(ew[i]));
    }
}

// ---------------------------------------------------------------------------
// Pull-mode aggregate + ReLU: 32 lanes per dst node, 3 dims/lane, no atomics.
// ---------------------------------------------------------------------------
__global__ __launch_bounds__(256) void k_agg(const float* __restrict__ support,
                                             const int* __restrict__ row_ptr,
                                             const int2* __restrict__ sorted,
                                             float* __restrict__ h) {
    const int g = blockIdx.x * 8 + (threadIdx.x >> 5);
    const int l = threadIdx.x & 31;
    if (g >= N_NODES) return;
    const int beg = row_ptr[g];
    const int end = row_ptr[g + 1];
    float a0 = 0.f, a1 = 0.f, a2 = 0.f;
    int e = beg;
    for (; e + 2 <= end; e += 2) {
        int2 s0 = sorted[e];
        int2 s1 = sorted[e + 1];
        const float* r0 = support + (size_t)s0.x * NHID;
        const float* r1 = support + (size_t)s1.x * NHID;
        float w0 = __int_as_float(s0.y);
        float w1 = __int_as_float(s1.y);
        a0 = fmaf(w0, r0[l], a0);
        a1 = fmaf(w0, r0[l + 32], a1);
        a2 = fmaf(w0, r0[l + 64], a2);
        a0 = fmaf(w1, r1[l], a0);
        a1 = fmaf(w1, r1[l + 32], a1);
        a2 = fmaf(w1, r1[l + 64], a2);
    }
    if (e < end) {
        int2 s0 = sorted[e];
        const float* r0 = support + (size_t)s0.x * NHID;
        float w0 = __int_as_float(s0.y);
        a0 = fmaf(w0, r0[l], a0);
        a1 = fmaf(w0, r0[l + 32], a1);
        a2 = fmaf(w0, r0[l + 64], a2);
    }
    float* hr = h + (size_t)g * NHID;
    hr[l] = fmaxf(a0, 0.f);
    hr[l + 32] = fmaxf(a1, 0.f);
    hr[l + 64] = fmaxf(a2, 0.f);
}

// ---------------------------------------------------------------------------
// Fallback (small workspace): atomic scatter-add aggregate, then ReLU.
// ---------------------------------------------------------------------------
__global__ __launch_bounds__(256) void k_agg_atomic(const float* __restrict__ support,
                                                    const int* __restrict__ src,
                                                    const int* __restrict__ dst,
                                                    const float* __restrict__ ew,
                                                    float* __restrict__ h) {
    int e = blockIdx.x * 8 + (threadIdx.x >> 5);
    int l = threadIdx.x & 31;
    if (e >= N_EDGES) return;
    int s = src[e];
    int d = dst[e];
    float w = ew[e];
    const float* r = support + (size_t)s * NHID;
    float* hd = h + (size_t)d * NHID;
    atomicAdd(&hd[l], w * r[l]);
    atomicAdd(&hd[l + 32], w * r[l + 32]);
    atomicAdd(&hd[l + 64], w * r[l + 64]);
}

__global__ __launch_bounds__(256) void k_relu(float* __restrict__ h) {
    int i = blockIdx.x * 256 + threadIdx.x;
    if (i < N_NODES * NHID) h[i] = fmaxf(h[i], 0.f);
}

// ---------------------------------------------------------------------------
// GEMM2 + bias + log_softmax fused. One row per wave per iter; lanes 0..39 = classes.
// W2 staged once per block in LDS; 4 h-rows staged per iteration.
// ---------------------------------------------------------------------------
__global__ __launch_bounds__(256) void k_gemm2(const float* __restrict__ h,
                                               const float* __restrict__ W2,
                                               const float* __restrict__ b2,
                                               float* __restrict__ out) {
    __shared__ float w2s[NHID * NCLASS + 64];  // +64 pad: lanes 40..63 read junk, masked later
    __shared__ float b2s[NCLASS];
    __shared__ float hb[4][NHID];
    const int tid = threadIdx.x;
    for (int i = tid; i < NHID * NCLASS; i += 256) w2s[i] = W2[i];
    if (tid < NCLASS) b2s[tid] = b2[tid];
    const int wid = tid >> 6;
    const int lane = tid & 63;

    for (int rbase = blockIdx.x * 4; rbase < N_NODES; rbase += gridDim.x * 4) {
        __syncthreads();  // protect hb from previous iter's readers; also fences w2s on iter 0
        for (int i = tid; i < 4 * NHID; i += 256) {
            int r = i / NHID, c = i - r * NHID;
            int row = rbase + r;
            hb[r][c] = (row < N_NODES) ? h[(size_t)row * NHID + c] : 0.f;
        }
        __syncthreads();
        const int row = rbase + wid;
        float acc = (lane < NCLASS) ? b2s[lane] : 0.f;
#pragma unroll 8
        for (int k = 0; k < NHID; ++k)
            acc = fmaf(hb[wid][k], w2s[k * NCLASS + lane], acc);
        float m = (lane < NCLASS) ? acc : -1e30f;
#pragma unroll
        for (int off = 32; off > 0; off >>= 1) m = fmaxf(m, __shfl_xor(m, off));
        float ev = (lane < NCLASS) ? __expf(acc - m) : 0.f;
        float s = ev;
#pragma unroll
        for (int off = 32; off > 0; off >>= 1) s += __shfl_xor(s, off);
        if (row < N_NODES && lane < NCLASS)
            out[(size_t)row * NCLASS + lane] = acc - m - __logf(s);
    }
}

// ---------------------------------------------------------------------------
extern "C" void kernel_launch(void* const* d_in, const int* in_sizes, int n_in,
                              void* d_out, int out_size, void* d_ws, size_t ws_size,
                              hipStream_t stream) {
    const float* x  = (const float*)d_in[0];
    const int* ei   = (const int*)d_in[1];
    const float* ew = (const float*)d_in[2];
    const float* W1 = (const float*)d_in[3];
    const float* b1 = (const float*)d_in[4];
    const float* W2 = (const float*)d_in[5];
    const float* b2 = (const float*)d_in[6];
    float* out = (float*)d_out;
    const int* src = ei;
    const int* dst = ei + N_EDGES;

    char* ws = (char*)d_ws;
    size_t off = 0;
    auto alloc = [&](size_t bytes) -> void* {
        void* p = ws + off;
        off = (off + bytes + 255) & ~(size_t)255;
        return p;
    };
    float* support = (float*)alloc((size_t)N_NODES * NHID * 4);
    float* h       = (float*)alloc((size_t)N_NODES * NHID * 4);
    int* deg       = (int*)alloc((size_t)N_NODES * 4);
    int* row_ptr   = (int*)alloc((size_t)(N_NODES + 1) * 4);
    int* cursor    = (int*)alloc((size_t)N_NODES * 4);
    int2* sorted   = (int2*)alloc((size_t)N_EDGES * 8);
    const bool csr_fits = (off <= ws_size);

    k_gemm1<<<(N_NODES + 63) / 64, 256, 0, stream>>>(x, W1, b1, support);

    if (csr_fits) {
        hipMemsetAsync(deg, 0, (size_t)N_NODES * sizeof(int), stream);
        k_hist<<<(N_EDGES + 255) / 256, 256, 0, stream>>>(dst, deg);
        k_scan<<<1, 1024, 0, stream>>>(deg, row_ptr, cursor);
        k_scatter<<<(N_EDGES + 255) / 256, 256, 0, stream>>>(src, dst, ew, cursor, sorted);
        k_agg<<<(N_NODES + 7) / 8, 256, 0, stream>>>(support, row_ptr, sorted, h);
    } else {
        hipMemsetAsync(h, 0, (size_t)N_NODES * NHID * 4, stream);
        k_agg_atomic<<<(N_EDGES + 7) / 8, 256, 0, stream>>>(support, src, dst, ew, h);
        k_relu<<<(N_NODES * NHID + 255) / 256, 256, 0, stream>>>(h);
    }

    k_gemm2<<<3125, 256, 0, stream>>>(h, W2, b2, out);
}

// Round 2
// 216.463 us; speedup vs baseline: 1.4905x; 1.4905x over previous
//
#include <hip/hip_runtime.h>
#include <math.h>

static constexpr int N_NODES = 50000;
static constexpr int N_EDGES = 800000;
static constexpr int NFEAT = 512;
static constexpr int NHID = 96;
static constexpr int NCLASS = 40;
static constexpr int SCAN_BLOCKS = (N_NODES + 255) / 256;  // 196

typedef __bf16 bf16_t;
typedef __attribute__((ext_vector_type(8))) __bf16 bf16x8;
typedef __attribute__((ext_vector_type(4))) float f32x4;

// ---------------------------------------------------------------------------
// One-time: W1 [512][96] f32  ->  W1t [96][512] bf16 (transpose + convert)
// ---------------------------------------------------------------------------
__global__ __launch_bounds__(256) void k_w1t(const float* __restrict__ W1,
                                             bf16_t* __restrict__ w1t) {
    int e = blockIdx.x * 256 + threadIdx.x;
    if (e < NFEAT * NHID) {
        int k = e / NHID;
        int n = e - k * NHID;
        w1t[(size_t)n * NFEAT + k] = (bf16_t)W1[e];
    }
}

// ---------------------------------------------------------------------------
// GEMM1 (bf16 MFMA): support[M,96] = x[M,512] @ W1[512,96] + b1
// Block = 64 rows, 4 waves; wave owns 16 rows x 96 cols (6 n-tiles of 16).
// A: direct global->reg f32, cvt to bf16 (each row used by exactly one wave).
// B: W1t staged per K-tile (64) into XOR-swizzled LDS (T2), bf16.
// MFMA: v_mfma_f32_16x16x32_bf16, 12 per wave per K-tile.
// ---------------------------------------------------------------------------
static __device__ inline bf16x8 cvt8(float4 u, float4 v) {
    bf16x8 r;
    r[0] = (bf16_t)u.x; r[1] = (bf16_t)u.y; r[2] = (bf16_t)u.z; r[3] = (bf16_t)u.w;
    r[4] = (bf16_t)v.x; r[5] = (bf16_t)v.y; r[6] = (bf16_t)v.z; r[7] = (bf16_t)v.w;
    return r;
}

__global__ __launch_bounds__(256) void k_gemm1_mfma(const float* __restrict__ x,
                                                    const bf16_t* __restrict__ w1t,
                                                    const float* __restrict__ b1,
                                                    float* __restrict__ support) {
    __shared__ bf16_t Bs[NHID * 64];  // [n][k] 96x64 bf16 = 12KB, XOR-swizzled
    const int tid = threadIdx.x;
    const int w = tid >> 6;
    const int l = tid & 63;
    const int row0 = blockIdx.x * 64;

    int arow = row0 + w * 16 + (l & 15);
    if (arow > N_NODES - 1) arow = N_NODES - 1;  // clamp: dup loads, masked store
    const float* ap = x + (size_t)arow * NFEAT + ((l >> 4) << 3);

    f32x4 acc[6];
#pragma unroll
    for (int nt = 0; nt < 6; ++nt) acc[nt] = (f32x4){0.f, 0.f, 0.f, 0.f};

    for (int kt = 0; kt < NFEAT; kt += 64) {
        // A loads for both K-steps of this tile (issued early, hide under staging)
        float4 a0 = *reinterpret_cast<const float4*>(ap + kt);
        float4 a1 = *reinterpret_cast<const float4*>(ap + kt + 4);
        float4 a2 = *reinterpret_cast<const float4*>(ap + kt + 32);
        float4 a3 = *reinterpret_cast<const float4*>(ap + kt + 36);

        __syncthreads();  // previous tile's B reads complete
        // stage B tile: 96 rows x 128B, swizzled writes (reg-staged, both sides XOR)
#pragma unroll
        for (int p = 0; p < 3; ++p) {
            int idx = tid + p * 256;      // 0..767
            int n = idx >> 3;             // 0..95
            int c = idx & 7;              // 16B chunk in row
            uint4 v = *reinterpret_cast<const uint4*>(w1t + (size_t)n * NFEAT + kt + c * 8);
            int ba = (n * 128 + c * 16) ^ ((n & 7) << 4);
            *reinterpret_cast<uint4*>(reinterpret_cast<char*>(Bs) + ba) = v;
        }
        __syncthreads();

        bf16x8 af0 = cvt8(a0, a1);
        bf16x8 af1 = cvt8(a2, a3);
        const int koff = (l >> 4) << 4;  // kblk*16 bytes
#pragma unroll
        for (int nt = 0; nt < 6; ++nt) {
            int n = nt * 16 + (l & 15);
            int ba0 = (n * 128 + koff) ^ ((n & 7) << 4);
            int ba1 = (n * 128 + 64 + koff) ^ ((n & 7) << 4);
            bf16x8 bf0 = *reinterpret_cast<const bf16x8*>(reinterpret_cast<const char*>(Bs) + ba0);
            bf16x8 bf1 = *reinterpret_cast<const bf16x8*>(reinterpret_cast<const char*>(Bs) + ba1);
            acc[nt] = __builtin_amdgcn_mfma_f32_16x16x32_bf16(af0, bf0, acc[nt], 0, 0, 0);
            acc[nt] = __builtin_amdgcn_mfma_f32_16x16x32_bf16(af1, bf1, acc[nt], 0, 0, 0);
        }
    }

    // Epilogue: C layout col=lane&15, row=(lane>>4)*4+reg (m89-verified mapping)
    const int col16 = l & 15;
    const int rq = l >> 4;
#pragma unroll
    for (int nt = 0; nt < 6; ++nt) {
        int col = nt * 16 + col16;
        float bv = b1[col];
#pragma unroll
        for (int r = 0; r < 4; ++r) {
            int row = row0 + w * 16 + rq * 4 + r;
            if (row < N_NODES)
                support[(size_t)row * NHID + col] = acc[nt][r] + bv;
        }
    }
}

// ---------------------------------------------------------------------------
// CSR build: histogram -> hierarchical scan (3 kernels) -> counting-sort scatter
// ---------------------------------------------------------------------------
__global__ __launch_bounds__(256) void k_hist(const int* __restrict__ dst,
                                              int* __restrict__ deg) {
    int i = blockIdx.x * 256 + threadIdx.x;
    if (i < N_EDGES) atomicAdd(&deg[dst[i]], 1);
}

__global__ __launch_bounds__(256) void k_scan1(const int* __restrict__ deg,
                                               int* __restrict__ row_ptr,
                                               int* __restrict__ blk_sum) {
    __shared__ int wsum[4];
    const int t = threadIdx.x;
    const int lane = t & 63, wid = t >> 6;
    const int i = blockIdx.x * 256 + t;
    int v = (i < N_NODES) ? deg[i] : 0;
    int xv = v;
#pragma unroll
    for (int off = 1; off < 64; off <<= 1) {
        int y = __shfl_up(xv, off);
        if (lane >= off) xv += y;
    }
    if (lane == 63) wsum[wid] = xv;
    __syncthreads();
    if (t == 0) {
        int s = 0;
#pragma unroll
        for (int j = 0; j < 4; ++j) { int tmp = wsum[j]; wsum[j] = s; s += tmp; }
        blk_sum[blockIdx.x] = s;
    }
    __syncthreads();
    if (i < N_NODES) row_ptr[i] = wsum[wid] + xv - v;  // block-local exclusive
}

__global__ __launch_bounds__(256) void k_scan2(const int* __restrict__ blk_sum,
                                               int* __restrict__ blk_off,
                                               int* __restrict__ row_ptr) {
    __shared__ int wsum[4];
    const int t = threadIdx.x;
    const int lane = t & 63, wid = t >> 6;
    int v = (t < SCAN_BLOCKS) ? blk_sum[t] : 0;
    int xv = v;
#pragma unroll
    for (int off = 1; off < 64; off <<= 1) {
        int y = __shfl_up(xv, off);
        if (lane >= off) xv += y;
    }
    if (lane == 63) wsum[wid] = xv;
    __syncthreads();
    if (t == 0) {
        int s = 0;
#pragma unroll
        for (int j = 0; j < 4; ++j) { int tmp = wsum[j]; wsum[j] = s; s += tmp; }
        row_ptr[N_NODES] = s;  // grand total (= N_EDGES)
    }
    __syncthreads();
    if (t < SCAN_BLOCKS) blk_off[t] = wsum[wid] + xv - v;
}

__global__ __launch_bounds__(256) void k_scan3(int* __restrict__ row_ptr,
                                               int* __restrict__ cursor,
                                               const int* __restrict__ blk_off) {
    int i = blockIdx.x * 256 + threadIdx.x;
    if (i < N_NODES) {
        int v = row_ptr[i] + blk_off[blockIdx.x];
        row_ptr[i] = v;
        cursor[i] = v;
    }
}

__global__ __launch_bounds__(256) void k_scatter(const int* __restrict__ src,
                                                 const int* __restrict__ dst,
                                                 const float* __restrict__ ew,
                                                 int* __restrict__ cursor,
                                                 int2* __restrict__ sorted) {
    int i = blockIdx.x * 256 + threadIdx.x;
    if (i < N_EDGES) {
        int d = dst[i];
        int pos = atomicAdd(&cursor[d], 1);
        sorted[pos] = make_int2(src[i], __float_as_int(ew[i]));
    }
}

// ---------------------------------------------------------------------------
// Pull-mode aggregate + ReLU: 32 lanes per dst node, 3 dims/lane, no atomics.
// ---------------------------------------------------------------------------
__global__ __launch_bounds__(256) void k_agg(const float* __restrict__ support,
                                             const int* __restrict__ row_ptr,
                                             const int2* __restrict__ sorted,
                                             float* __restrict__ h) {
    const int g = blockIdx.x * 8 + (threadIdx.x >> 5);
    const int l = threadIdx.x & 31;
    if (g >= N_NODES) return;
    const int beg = row_ptr[g];
    const int end = row_ptr[g + 1];
    float a0 = 0.f, a1 = 0.f, a2 = 0.f;
    int e = beg;
    for (; e + 2 <= end; e += 2) {
        int2 s0 = sorted[e];
        int2 s1 = sorted[e + 1];
        const float* r0 = support + (size_t)s0.x * NHID;
        const float* r1 = support + (size_t)s1.x * NHID;
        float w0 = __int_as_float(s0.y);
        float w1 = __int_as_float(s1.y);
        a0 = fmaf(w0, r0[l], a0);
        a1 = fmaf(w0, r0[l + 32], a1);
        a2 = fmaf(w0, r0[l + 64], a2);
        a0 = fmaf(w1, r1[l], a0);
        a1 = fmaf(w1, r1[l + 32], a1);
        a2 = fmaf(w1, r1[l + 64], a2);
    }
    if (e < end) {
        int2 s0 = sorted[e];
        const float* r0 = support + (size_t)s0.x * NHID;
        float w0 = __int_as_float(s0.y);
        a0 = fmaf(w0, r0[l], a0);
        a1 = fmaf(w0, r0[l + 32], a1);
        a2 = fmaf(w0, r0[l + 64], a2);
    }
    float* hr = h + (size_t)g * NHID;
    hr[l] = fmaxf(a0, 0.f);
    hr[l + 32] = fmaxf(a1, 0.f);
    hr[l + 64] = fmaxf(a2, 0.f);
}

// ---------------------------------------------------------------------------
// Fallback (small workspace): atomic scatter-add aggregate, then ReLU.
// ---------------------------------------------------------------------------
__global__ __launch_bounds__(256) void k_agg_atomic(const float* __restrict__ support,
                                                    const int* __restrict__ src,
                                                    const int* __restrict__ dst,
                                                    const float* __restrict__ ew,
                                                    float* __restrict__ h) {
    int e = blockIdx.x * 8 + (threadIdx.x >> 5);
    int l = threadIdx.x & 31;
    if (e >= N_EDGES) return;
    int s = src[e];
    int d = dst[e];
    float w = ew[e];
    const float* r = support + (size_t)s * NHID;
    float* hd = h + (size_t)d * NHID;
    atomicAdd(&hd[l], w * r[l]);
    atomicAdd(&hd[l + 32], w * r[l + 32]);
    atomicAdd(&hd[l + 64], w * r[l + 64]);
}

__global__ __launch_bounds__(256) void k_relu(float* __restrict__ h) {
    int i = blockIdx.x * 256 + threadIdx.x;
    if (i < N_NODES * NHID) h[i] = fmaxf(h[i], 0.f);
}

// ---------------------------------------------------------------------------
// GEMM2 + bias + log_softmax fused. One row per wave per iter; lanes 0..39 = classes.
// ---------------------------------------------------------------------------
__global__ __launch_bounds__(256) void k_gemm2(const float* __restrict__ h,
                                               const float* __restrict__ W2,
                                               const float* __restrict__ b2,
                                               float* __restrict__ out) {
    __shared__ float w2s[NHID * NCLASS + 64];  // +64 pad: lanes 40..63 read junk, masked
    __shared__ float b2s[NCLASS];
    __shared__ float hb[4][NHID];
    const int tid = threadIdx.x;
    for (int i = tid; i < NHID * NCLASS; i += 256) w2s[i] = W2[i];
    if (tid < NCLASS) b2s[tid] = b2[tid];
    const int wid = tid >> 6;
    const int lane = tid & 63;

    for (int rbase = blockIdx.x * 4; rbase < N_NODES; rbase += gridDim.x * 4) {
        __syncthreads();
        for (int i = tid; i < 4 * NHID; i += 256) {
            int r = i / NHID, c = i - r * NHID;
            int row = rbase + r;
            hb[r][c] = (row < N_NODES) ? h[(size_t)row * NHID + c] : 0.f;
        }
        __syncthreads();
        const int row = rbase + wid;
        float acc = (lane < NCLASS) ? b2s[lane] : 0.f;
#pragma unroll 8
        for (int k = 0; k < NHID; ++k)
            acc = fmaf(hb[wid][k], w2s[k * NCLASS + lane], acc);
        float m = (lane < NCLASS) ? acc : -1e30f;
#pragma unroll
        for (int off = 32; off > 0; off >>= 1) m = fmaxf(m, __shfl_xor(m, off));
        float ev = (lane < NCLASS) ? __expf(acc - m) : 0.f;
        float s = ev;
#pragma unroll
        for (int off = 32; off > 0; off >>= 1) s += __shfl_xor(s, off);
        if (row < N_NODES && lane < NCLASS)
            out[(size_t)row * NCLASS + lane] = acc - m - __logf(s);
    }
}

// ---------------------------------------------------------------------------
extern "C" void kernel_launch(void* const* d_in, const int* in_sizes, int n_in,
                              void* d_out, int out_size, void* d_ws, size_t ws_size,
                              hipStream_t stream) {
    const float* x  = (const float*)d_in[0];
    const int* ei   = (const int*)d_in[1];
    const float* ew = (const float*)d_in[2];
    const float* W1 = (const float*)d_in[3];
    const float* b1 = (const float*)d_in[4];
    const float* W2 = (const float*)d_in[5];
    const float* b2 = (const float*)d_in[6];
    float* out = (float*)d_out;
    const int* src = ei;
    const int* dst = ei + N_EDGES;

    char* ws = (char*)d_ws;
    size_t off = 0;
    auto alloc = [&](size_t bytes) -> void* {
        void* p = ws + off;
        off = (off + bytes + 255) & ~(size_t)255;
        return p;
    };
    float* support = (float*)alloc((size_t)N_NODES * NHID * 4);
    float* h       = (float*)alloc((size_t)N_NODES * NHID * 4);
    bf16_t* w1t    = (bf16_t*)alloc((size_t)NHID * NFEAT * 2);
    int* deg       = (int*)alloc((size_t)N_NODES * 4);
    int* row_ptr   = (int*)alloc((size_t)(N_NODES + 1) * 4);
    int* cursor    = (int*)alloc((size_t)N_NODES * 4);
    int* blk_sum   = (int*)alloc(256 * 4);
    int* blk_off   = (int*)alloc(256 * 4);
    int2* sorted   = (int2*)alloc((size_t)N_EDGES * 8);
    const bool csr_fits = (off <= ws_size);

    k_w1t<<<(NFEAT * NHID + 255) / 256, 256, 0, stream>>>(W1, w1t);
    k_gemm1_mfma<<<(N_NODES + 63) / 64, 256, 0, stream>>>(x, w1t, b1, support);

    if (csr_fits) {
        hipMemsetAsync(deg, 0, (size_t)N_NODES * sizeof(int), stream);
        k_hist<<<(N_EDGES + 255) / 256, 256, 0, stream>>>(dst, deg);
        k_scan1<<<SCAN_BLOCKS, 256, 0, stream>>>(deg, row_ptr, blk_sum);
        k_scan2<<<1, 256, 0, stream>>>(blk_sum, blk_off, row_ptr);
        k_scan3<<<SCAN_BLOCKS, 256, 0, stream>>>(row_ptr, cursor, blk_off);
        k_scatter<<<(N_EDGES + 255) / 256, 256, 0, stream>>>(src, dst, ew, cursor, sorted);
        k_agg<<<(N_NODES + 7) / 8, 256, 0, stream>>>(support, row_ptr, sorted, h);
    } else {
        hipMemsetAsync(h, 0, (size_t)N_NODES * NHID * 4, stream);
        k_agg_atomic<<<(N_EDGES + 7) / 8, 256, 0, stream>>>(support, src, dst, ew, h);
        k_relu<<<(N_NODES * NHID + 255) / 256, 256, 0, stream>>>(h);
    }

    k_gemm2<<<3125, 256, 0, stream>>>(h, W2, b2, out);
}